// Round 1
// baseline (13376.111 us; speedup 1.0000x reference)
//
#include <hip/hip_runtime.h>
#include <stdint.h>

// 2-layer bidirectional LSTM, T=512 B=64 D=512 H=512.
// Phase kernel: one kernel per layer; 2 dirs x 64 WGs; per-WG 32 gate cols;
// per-step cross-WG h broadcast via global bf16 buffer + flag sync.

#define TT 512
#define BATCH 64
#define HH 512
#define NWG 64       // workgroups per direction
#define NCOLS 32     // gate columns per WG (4 gates x 8 h-cols)

typedef __attribute__((ext_vector_type(8))) short vshort8;
typedef __attribute__((ext_vector_type(4))) float vfloat4;

__device__ __forceinline__ vfloat4 mfma16(vshort8 a, vshort8 b, vfloat4 c) {
    return __builtin_amdgcn_mfma_f32_16x16x32_bf16(a, b, c, 0, 0, 0);
}

__device__ __forceinline__ float sigmoidf_(float x) {
    return 1.f / (1.f + __expf(-x));
}
__device__ __forceinline__ float tanhf_(float x) {
    float e = __expf(2.f * x);
    return 1.f - 2.f / (e + 1.f);
}
__device__ __forceinline__ unsigned short f2bf(float f) {
    uint32_t u = __float_as_uint(f);
    uint32_t r = (u + 0x7fffu + ((u >> 16) & 1u)) >> 16;
    return (unsigned short)r;
}

__global__ void cvt_f32_bf16(const float* __restrict__ src,
                             unsigned short* __restrict__ dst, int n) {
    int i = (blockIdx.x * blockDim.x + threadIdx.x) * 4;
    if (i + 3 < n) {
        float4 v = *(const float4*)(src + i);
        uint2 p;
        p.x = (uint32_t)f2bf(v.x) | ((uint32_t)f2bf(v.y) << 16);
        p.y = (uint32_t)f2bf(v.z) | ((uint32_t)f2bf(v.w) << 16);
        *(uint2*)(dst + i) = p;
    }
}

// DIN: input feature size of this layer (512 or 1024).
// WRITE_BF16: phase A writes bf16 o0; else writes fp32 o1 to d_out.
template <int DIN, bool WRITE_BF16>
__launch_bounds__(256, 1)
__global__ void lstm_phase(const unsigned short* __restrict__ A,   // [T][B][DIN] bf16
                           const unsigned short* __restrict__ Wi,  // [2][4H][DIN] bf16
                           const unsigned short* __restrict__ Wh,  // [2][4H][H] bf16
                           const float* __restrict__ bias,         // [2][4H] f32
                           unsigned short* __restrict__ hbuf,      // [2][2][B][H] bf16
                           int* __restrict__ flags,                // [2][T]
                           unsigned short* __restrict__ obf,       // [T][B][2H] bf16 (phase A)
                           float* __restrict__ of32,               // [T][B][2H] f32 (phase B)
                           float* __restrict__ hn,                 // [2][B][H] f32
                           float* __restrict__ cn)                 // [2][B][H] f32
{
    __shared__ unsigned short Wlds[NCOLS * DIN];  // Wi slice, 32KB or 64KB

    const int tid = threadIdx.x;
    const int dir = blockIdx.x >> 6;
    const int wg = blockIdx.x & 63;
    const int j0 = wg * 8;  // first h-column of this WG
    const int lane = tid & 63;
    const int wave = tid >> 6;

    // ---- stage Wi slice into LDS (swizzled: byte ^= (n&7)<<4) ----
    for (int chunk = tid; chunk < NCOLS * DIN / 8; chunk += 256) {
        int n = chunk / (DIN / 8);
        int k8 = (chunk % (DIN / 8)) * 8;
        int grow = (n >> 3) * HH + j0 + (n & 7);
        vshort8 v = *(const vshort8*)(Wi + ((size_t)dir * 4 * HH + grow) * DIN + k8);
        int byte = n * DIN * 2 + ((k8 * 2) ^ ((n & 7) << 4));
        *(vshort8*)((char*)Wlds + byte) = v;
    }
    __syncthreads();

    // ---- per-lane constants ----
    const int arow = wave * 16 + (lane & 15);       // A-fragment batch row
    const int kOff = (lane >> 4) * 8;               // k offset (elements)
    const int klane = (lane >> 4) * 16;             // k offset (bytes)
    const int n0 = lane & 15;                       // tile-0 column
    const int swz = (n0 & 7) << 4;
    const int nb0 = n0 * DIN * 2;
    const int nb1 = (16 + n0) * DIN * 2;
    const int grow0 = (n0 >> 3) * HH + j0 + (n0 & 7);        // gate 0/1 row
    const int grow1 = ((n0 >> 3) + 2) * HH + j0 + (n0 & 7);  // gate 2/3 row
    const float bias0 = bias[dir * 4 * HH + grow0];
    const float bias1 = bias[dir * 4 * HH + grow1];
    const unsigned short* whp0 = Wh + ((size_t)dir * 4 * HH + grow0) * HH + kOff;
    const unsigned short* whp1 = Wh + ((size_t)dir * 4 * HH + grow1) * HH + kOff;
    const bool lo = (lane & 8) == 0;
    const int j = lane & 7;
    const int jcol = j0 + j;
    const int hrowb = wave * 16 + ((lane >> 4) << 2);
    int* flagp = flags + dir * TT;

    float cstate[4] = {0.f, 0.f, 0.f, 0.f};

    for (int s = 0; s < TT; ++s) {
        const int t = dir ? (TT - 1 - s) : s;

        vfloat4 acc0, acc1;
        acc0[0] = acc0[1] = acc0[2] = acc0[3] = bias0;
        acc1[0] = acc1[1] = acc1[2] = acc1[3] = bias1;

        // ---- x part: gates += x_t @ Wi^T (no cross-WG dependency) ----
        const unsigned short* ap = A + ((size_t)t * BATCH + arow) * DIN + kOff;
#pragma unroll 8
        for (int kk = 0; kk < DIN / 32; ++kk) {
            vshort8 a = *(const vshort8*)(ap + kk * 32);
            int kb = kk * 64 + klane;
            vshort8 b0 = *(const vshort8*)((const char*)Wlds + nb0 + (kb ^ swz));
            vshort8 b1 = *(const vshort8*)((const char*)Wlds + nb1 + (kb ^ swz));
            acc0 = mfma16(a, b0, acc0);
            acc1 = mfma16(a, b1, acc1);
        }

        // ---- wait for previous step's h, then gates += h @ Wh^T ----
        if (s > 0) {
            if (tid == 0) {
                while (__hip_atomic_load(flagp + (s - 1), __ATOMIC_RELAXED,
                                         __HIP_MEMORY_SCOPE_AGENT) < NWG)
                    __builtin_amdgcn_s_sleep(2);
                __builtin_amdgcn_fence(__ATOMIC_ACQUIRE, "agent");
            }
            __syncthreads();
            const unsigned short* hp =
                hbuf + (((dir << 1) | ((s - 1) & 1)) * BATCH + arow) * HH + kOff;
#pragma unroll 8
            for (int kk = 0; kk < HH / 32; ++kk) {
                vshort8 a = *(const vshort8*)(hp + kk * 32);
                vshort8 b0 = *(const vshort8*)(whp0 + kk * 32);
                vshort8 b1 = *(const vshort8*)(whp1 + kk * 32);
                acc0 = mfma16(a, b0, acc0);
                acc1 = mfma16(a, b1, acc1);
            }
        }

        // ---- epilogue: exchange i/f and g/o halves, LSTM cell update ----
        float hval[4];
#pragma unroll
        for (int r = 0; r < 4; ++r) {
            float own0 = acc0[r], own1 = acc1[r];
            float oth0 = __shfl_xor(own0, 8, 64);
            float oth1 = __shfl_xor(own1, 8, 64);
            float iv = lo ? own0 : oth0;
            float fv = lo ? oth0 : own0;
            float gv = lo ? own1 : oth1;
            float ov = lo ? oth1 : own1;
            float cnew = sigmoidf_(fv) * cstate[r] + sigmoidf_(iv) * tanhf_(gv);
            cstate[r] = cnew;
            hval[r] = sigmoidf_(ov) * tanhf_(cnew);
        }

        // ---- stores: h broadcast buffer (bf16) + layer output ----
        unsigned short* hw = hbuf + (size_t)(((dir << 1) | (s & 1)) * BATCH) * HH;
        const int rA = lo ? 0 : 2;
#pragma unroll
        for (int q = 0; q < 2; ++q) {
            int r = rA + q, row = hrowb + r;
            unsigned short hb = f2bf(hval[r]);
            hw[row * HH + jcol] = hb;
            if constexpr (WRITE_BF16)
                obf[((size_t)t * BATCH + row) * (2 * HH) + dir * HH + jcol] = hb;
            else
                of32[((size_t)t * BATCH + row) * (2 * HH) + dir * HH + jcol] = hval[r];
        }
        if (s == TT - 1) {
#pragma unroll
            for (int q = 0; q < 2; ++q) {
                int r = rA + q, row = hrowb + r;
                hn[(dir * BATCH + row) * HH + jcol] = hval[r];
                cn[(dir * BATCH + row) * HH + jcol] = cstate[r];
            }
        }

        // ---- release: own stores done -> barrier -> flush L2 -> flag ----
        asm volatile("s_waitcnt vmcnt(0)" ::: "memory");
        __syncthreads();
        if (tid == 0) {
            __builtin_amdgcn_fence(__ATOMIC_RELEASE, "agent");
            atomicAdd(flagp + s, 1);
        }
    }
}

extern "C" void kernel_launch(void* const* d_in, const int* in_sizes, int n_in,
                              void* d_out, int out_size, void* d_ws, size_t ws_size,
                              hipStream_t stream) {
    const float* x = (const float*)d_in[0];
    const float* Wi0 = (const float*)d_in[1];
    const float* Wh0 = (const float*)d_in[2];
    const float* b0 = (const float*)d_in[3];
    const float* Wi1 = (const float*)d_in[4];
    const float* Wh1 = (const float*)d_in[5];
    const float* b1 = (const float*)d_in[6];

    char* ws = (char*)d_ws;
    // ws layout (bytes)
    int* flags = (int*)(ws + 0);                       // [2 layers][2 dirs][T] = 8192 B
    unsigned short* hbuf = (unsigned short*)(ws + 8192);        // 262144 B
    unsigned short* wi0b = (unsigned short*)(ws + 270336);      // 4 MB
    unsigned short* wh0b = (unsigned short*)(ws + 4464640);     // 4 MB
    unsigned short* wi1b = (unsigned short*)(ws + 8658944);     // 8 MB
    unsigned short* wh1b = (unsigned short*)(ws + 17047552);    // 4 MB
    unsigned short* xb = (unsigned short*)(ws + 21241856);      // 32 MB
    unsigned short* o0 = (unsigned short*)(ws + 54796288);      // 64 MB; total ~116 MB

    float* out = (float*)d_out;
    const size_t O1SZ = (size_t)TT * BATCH * 2 * HH;  // 33554432
    float* hn_base = out + O1SZ;
    float* cn_base = out + O1SZ + 4 * BATCH * HH;

    hipMemsetAsync(flags, 0, 8192, stream);

    // fp32 -> bf16 conversions (deterministic, rerun every call)
    {
        int n;
        n = TT * BATCH * 512;
        cvt_f32_bf16<<<n / 1024, 256, 0, stream>>>(x, xb, n);
        n = 2 * 2048 * 512;
        cvt_f32_bf16<<<n / 1024, 256, 0, stream>>>(Wi0, wi0b, n);
        cvt_f32_bf16<<<n / 1024, 256, 0, stream>>>(Wh0, wh0b, n);
        cvt_f32_bf16<<<n / 1024, 256, 0, stream>>>(Wh1, wh1b, n);
        n = 2 * 2048 * 1024;
        cvt_f32_bf16<<<n / 1024, 256, 0, stream>>>(Wi1, wi1b, n);
    }

    // phase A: layer 0 (reads xb, writes o0 bf16 + h_n/c_n dirs 0,1)
    lstm_phase<512, true><<<128, 256, 0, stream>>>(
        xb, wi0b, wh0b, b0, hbuf, flags, o0, nullptr, hn_base, cn_base);

    // phase B: layer 1 (reads o0, writes o1 fp32 + h_n/c_n dirs 2,3)
    lstm_phase<1024, false><<<128, 256, 0, stream>>>(
        o0, wi1b, wh1b, b1, hbuf, flags + 2 * TT, nullptr, out,
        hn_base + 2 * BATCH * HH, cn_base + 2 * BATCH * HH);
}

// Round 2
// 7528.293 us; speedup vs baseline: 1.7768x; 1.7768x over previous
//
#include <hip/hip_runtime.h>
#include <stdint.h>

// 2-layer bidirectional LSTM, T=512 B=64 D=512 H=512.
// Per layer: 2 dirs x 64 WGs; per-WG 32 gate cols; Wi+Wh slices in LDS;
// per-step cross-WG h broadcast through LLC via sc0|sc1 accesses + epoch flags
// (NO agent fences -- they invalidate the whole per-XCD L2 every step).

#define TT 512
#define BATCH 64
#define HH 512
#define NWG 64       // workgroups per direction
#define NCOLS 32     // gate columns per WG (4 gates x 8 h-cols)

typedef __attribute__((ext_vector_type(8))) short vshort8;
typedef __attribute__((ext_vector_type(4))) float vfloat4;

__device__ __forceinline__ vfloat4 mfma16(vshort8 a, vshort8 b, vfloat4 c) {
    return __builtin_amdgcn_mfma_f32_16x16x32_bf16(a, b, c, 0, 0, 0);
}

__device__ __forceinline__ float sigmoidf_(float x) {
    return 1.f / (1.f + __expf(-x));
}
__device__ __forceinline__ float tanhf_(float x) {
    float e = __expf(2.f * x);
    return 1.f - 2.f / (e + 1.f);
}
__device__ __forceinline__ unsigned short f2bf(float f) {
    uint32_t u = __float_as_uint(f);
    uint32_t r = (u + 0x7fffu + ((u >> 16) & 1u)) >> 16;
    return (unsigned short)r;
}

__global__ void cvt_f32_bf16(const float* __restrict__ src,
                             unsigned short* __restrict__ dst, int n) {
    int i = (blockIdx.x * blockDim.x + threadIdx.x) * 4;
    if (i + 3 < n) {
        float4 v = *(const float4*)(src + i);
        uint2 p;
        p.x = (uint32_t)f2bf(v.x) | ((uint32_t)f2bf(v.y) << 16);
        p.y = (uint32_t)f2bf(v.z) | ((uint32_t)f2bf(v.w) << 16);
        *(uint2*)(dst + i) = p;
    }
}

// DIN: input feature size of this layer (512 or 1024).
// WRITE_BF16: phase A writes bf16 o0; else writes fp32 o1 to d_out.
template <int DIN, bool WRITE_BF16>
__launch_bounds__(256, 1)
__global__ void lstm_phase(const unsigned short* __restrict__ A,   // [T][B][DIN] bf16
                           const unsigned short* __restrict__ Wi,  // [2][4H][DIN] bf16
                           const unsigned short* __restrict__ Wh,  // [2][4H][H] bf16
                           const float* __restrict__ bias,         // [2][4H] f32
                           unsigned short* __restrict__ hbuf,      // [2][2][B][H] bf16
                           int* __restrict__ flags,                // [2][NWG] epoch slots
                           unsigned short* __restrict__ obf,       // [T][B][2H] bf16 (phase A)
                           float* __restrict__ of32,               // [T][B][2H] f32 (phase B)
                           float* __restrict__ hn,                 // [2][B][H] f32
                           float* __restrict__ cn)                 // [2][B][H] f32
{
    __shared__ unsigned short Wlds[NCOLS * DIN];  // Wi slice, 32KB or 64KB
    __shared__ unsigned short Whlds[NCOLS * HH];  // Wh slice, 32KB

    const int tid = threadIdx.x;
    const int dir = blockIdx.x >> 6;
    const int wg = blockIdx.x & 63;
    const int j0 = wg * 8;  // first h-column of this WG
    const int lane = tid & 63;
    const int wave = tid >> 6;

    // ---- stage Wi slice into LDS (swizzled: byte ^= (n&7)<<4) ----
    for (int chunk = tid; chunk < NCOLS * DIN / 8; chunk += 256) {
        int n = chunk / (DIN / 8);
        int k8 = (chunk % (DIN / 8)) * 8;
        int grow = (n >> 3) * HH + j0 + (n & 7);
        vshort8 v = *(const vshort8*)(Wi + ((size_t)dir * 4 * HH + grow) * DIN + k8);
        int byte = n * DIN * 2 + ((k8 * 2) ^ ((n & 7) << 4));
        *(vshort8*)((char*)Wlds + byte) = v;
    }
    // ---- stage Wh slice into LDS (same layout, K=HH) ----
    for (int chunk = tid; chunk < NCOLS * HH / 8; chunk += 256) {
        int n = chunk / (HH / 8);
        int k8 = (chunk % (HH / 8)) * 8;
        int grow = (n >> 3) * HH + j0 + (n & 7);
        vshort8 v = *(const vshort8*)(Wh + ((size_t)dir * 4 * HH + grow) * HH + k8);
        int byte = n * HH * 2 + ((k8 * 2) ^ ((n & 7) << 4));
        *(vshort8*)((char*)Whlds + byte) = v;
    }
    __syncthreads();

    // ---- per-lane constants ----
    const int arow = wave * 16 + (lane & 15);       // A-fragment batch row
    const int kOff = (lane >> 4) * 8;               // k offset (elements)
    const int klane = (lane >> 4) * 16;             // k offset (bytes)
    const int n0 = lane & 15;                       // tile-0 column
    const int swz = (n0 & 7) << 4;
    const int nb0 = n0 * DIN * 2;
    const int nb1 = (16 + n0) * DIN * 2;
    const int nb0h = n0 * HH * 2;
    const int nb1h = (16 + n0) * HH * 2;
    const int grow0 = (n0 >> 3) * HH + j0 + (n0 & 7);        // gate 0/1 row
    const int grow1 = ((n0 >> 3) + 2) * HH + j0 + (n0 & 7);  // gate 2/3 row
    const float bias0 = bias[dir * 4 * HH + grow0];
    const float bias1 = bias[dir * 4 * HH + grow1];
    const bool lo = (lane & 8) == 0;
    const int j = lane & 7;
    const int jcol = j0 + j;
    const int hrowb = wave * 16 + ((lane >> 4) << 2);

    float cstate[4] = {0.f, 0.f, 0.f, 0.f};

    for (int s = 0; s < TT; ++s) {
        const int t = dir ? (TT - 1 - s) : s;

        vfloat4 acc0, acc1;
        acc0[0] = acc0[1] = acc0[2] = acc0[3] = bias0;
        acc1[0] = acc1[1] = acc1[2] = acc1[3] = bias1;

        // ---- x part: gates += x_t @ Wi^T (no cross-WG dependency) ----
        const unsigned short* ap = A + ((size_t)t * BATCH + arow) * DIN + kOff;
#pragma unroll 8
        for (int kk = 0; kk < DIN / 32; ++kk) {
            vshort8 a = *(const vshort8*)(ap + kk * 32);
            int kb = kk * 64 + klane;
            vshort8 b0 = *(const vshort8*)((const char*)Wlds + nb0 + (kb ^ swz));
            vshort8 b1 = *(const vshort8*)((const char*)Wlds + nb1 + (kb ^ swz));
            acc0 = mfma16(a, b0, acc0);
            acc1 = mfma16(a, b1, acc1);
        }

        // ---- wait for previous step's h (epoch slots), then gates += h @ Wh^T ----
        if (s > 0) {
            if (wave == 0) {
                const int* slotp = flags + dir * NWG + lane;  // lane l watches WG l
                for (;;) {
                    int v;
                    asm volatile(
                        "global_load_dword %0, %1, off sc0 sc1\n\t"
                        "s_waitcnt vmcnt(0)"
                        : "=v"(v) : "v"(slotp) : "memory");
                    if (!__any(v < s)) break;
                    __builtin_amdgcn_s_sleep(1);
                }
            }
            __syncthreads();

            const unsigned short* hp =
                hbuf + (((dir << 1) | ((s - 1) & 1)) * BATCH + arow) * HH + kOff;
            vshort8 ha[HH / 32];
#pragma unroll
            for (int kk = 0; kk < HH / 32; ++kk)
                asm volatile("global_load_dwordx4 %0, %1, off sc0 sc1"
                             : "=v"(ha[kk]) : "v"(hp + kk * 32) : "memory");
            asm volatile("s_waitcnt vmcnt(0)" ::: "memory");
            __builtin_amdgcn_sched_barrier(0);
#pragma unroll
            for (int kk = 0; kk < HH / 32; ++kk) {
                int kb = kk * 64 + klane;
                vshort8 b0 = *(const vshort8*)((const char*)Whlds + nb0h + (kb ^ swz));
                vshort8 b1 = *(const vshort8*)((const char*)Whlds + nb1h + (kb ^ swz));
                acc0 = mfma16(ha[kk], b0, acc0);
                acc1 = mfma16(ha[kk], b1, acc1);
            }
        }

        // ---- epilogue: exchange i/f and g/o halves, LSTM cell update ----
        float hval[4];
#pragma unroll
        for (int r = 0; r < 4; ++r) {
            float own0 = acc0[r], own1 = acc1[r];
            float oth0 = __shfl_xor(own0, 8, 64);
            float oth1 = __shfl_xor(own1, 8, 64);
            float iv = lo ? own0 : oth0;
            float fv = lo ? oth0 : own0;
            float gv = lo ? own1 : oth1;
            float ov = lo ? oth1 : own1;
            float cnew = sigmoidf_(fv) * cstate[r] + sigmoidf_(iv) * tanhf_(gv);
            cstate[r] = cnew;
            hval[r] = sigmoidf_(ov) * tanhf_(cnew);
        }

        // ---- stores: h broadcast buffer (sc0|sc1, LLC-coherent) + layer output ----
        unsigned short* hw = hbuf + (size_t)(((dir << 1) | (s & 1)) * BATCH) * HH;
        const int rA = lo ? 0 : 2;
#pragma unroll
        for (int q = 0; q < 2; ++q) {
            int r = rA + q, row = hrowb + r;
            unsigned short hb = f2bf(hval[r]);
            unsigned short* hwp = hw + row * HH + jcol;
            uint32_t hb32 = hb;
            asm volatile("global_store_short %0, %1, off sc0 sc1"
                         :: "v"(hwp), "v"(hb32) : "memory");
            if constexpr (WRITE_BF16)
                obf[((size_t)t * BATCH + row) * (2 * HH) + dir * HH + jcol] = hb;
            else
                of32[((size_t)t * BATCH + row) * (2 * HH) + dir * HH + jcol] = hval[r];
        }
        if (s == TT - 1) {
#pragma unroll
            for (int q = 0; q < 2; ++q) {
                int r = rA + q, row = hrowb + r;
                hn[(dir * BATCH + row) * HH + jcol] = hval[r];
                cn[(dir * BATCH + row) * HH + jcol] = cstate[r];
            }
        }

        // ---- release: drain own stores -> barrier -> post epoch slot ----
        asm volatile("s_waitcnt vmcnt(0)" ::: "memory");
        __syncthreads();
        if (tid == 0) {
            int* myslot = flags + dir * NWG + wg;
            int ep = s + 1;
            asm volatile("global_store_dword %0, %1, off sc0 sc1"
                         :: "v"(myslot), "v"(ep) : "memory");
        }
    }
}

extern "C" void kernel_launch(void* const* d_in, const int* in_sizes, int n_in,
                              void* d_out, int out_size, void* d_ws, size_t ws_size,
                              hipStream_t stream) {
    const float* x = (const float*)d_in[0];
    const float* Wi0 = (const float*)d_in[1];
    const float* Wh0 = (const float*)d_in[2];
    const float* b0 = (const float*)d_in[3];
    const float* Wi1 = (const float*)d_in[4];
    const float* Wh1 = (const float*)d_in[5];
    const float* b1 = (const float*)d_in[6];

    char* ws = (char*)d_ws;
    // ws layout (bytes)
    int* flags = (int*)(ws + 0);                       // [2 layers][2 dirs][NWG] = 1024 B
    unsigned short* hbuf = (unsigned short*)(ws + 8192);        // 262144 B
    unsigned short* wi0b = (unsigned short*)(ws + 270336);      // 4 MB
    unsigned short* wh0b = (unsigned short*)(ws + 4464640);     // 4 MB
    unsigned short* wi1b = (unsigned short*)(ws + 8658944);     // 8 MB
    unsigned short* wh1b = (unsigned short*)(ws + 17047552);    // 4 MB
    unsigned short* xb = (unsigned short*)(ws + 21241856);      // 32 MB
    unsigned short* o0 = (unsigned short*)(ws + 54796288);      // 64 MB; total ~116 MB

    float* out = (float*)d_out;
    const size_t O1SZ = (size_t)TT * BATCH * 2 * HH;  // 33554432
    float* hn_base = out + O1SZ;
    float* cn_base = out + O1SZ + 4 * BATCH * HH;

    hipMemsetAsync(flags, 0, 1024, stream);

    // fp32 -> bf16 conversions (deterministic, rerun every call)
    {
        int n;
        n = TT * BATCH * 512;
        cvt_f32_bf16<<<n / 1024, 256, 0, stream>>>(x, xb, n);
        n = 2 * 2048 * 512;
        cvt_f32_bf16<<<n / 1024, 256, 0, stream>>>(Wi0, wi0b, n);
        cvt_f32_bf16<<<n / 1024, 256, 0, stream>>>(Wh0, wh0b, n);
        cvt_f32_bf16<<<n / 1024, 256, 0, stream>>>(Wh1, wh1b, n);
        n = 2 * 2048 * 1024;
        cvt_f32_bf16<<<n / 1024, 256, 0, stream>>>(Wi1, wi1b, n);
    }

    // phase A: layer 0 (reads xb, writes o0 bf16 + h_n/c_n dirs 0,1)
    lstm_phase<512, true><<<128, 256, 0, stream>>>(
        xb, wi0b, wh0b, b0, hbuf, flags, o0, nullptr, hn_base, cn_base);

    // phase B: layer 1 (reads o0, writes o1 fp32 + h_n/c_n dirs 2,3)
    lstm_phase<1024, false><<<128, 256, 0, stream>>>(
        o0, wi1b, wh1b, b1, hbuf, flags + 2 * NWG, nullptr, out,
        hn_base + 2 * BATCH * HH, cn_base + 2 * BATCH * HH);
}